// Round 1
// baseline (327.744 us; speedup 1.0000x reference)
//
#include <hip/hip_runtime.h>
#include <hip/hip_bf16.h>
#include <cstdint>

// ---------------------------------------------------------------------------
// WindowAttention: B windows (2048), N=64 tokens, DIM=192, H=6 heads, d=32.
// Pipeline: prep (weights->bf16 [n][k], comb = rel_bias+mask)
//           qkv  (per-window MFMA GEMM -> Q,K,V bf16 (B,H,N,d))
//           attn (per (window,head): QK^T, softmax in regs, PV)
//           proj (per-window MFMA GEMM -> fp32 out + bias)
// All matmuls: v_mfma_f32_16x16x32_bf16, fp32 accumulate. Softmax fp32.
// ---------------------------------------------------------------------------

#define NTOK 64
#define NH 6
#define HD 32
#define WDIM 192
#define SCALE 0.17677669529663689f

typedef __bf16 bf16x8 __attribute__((ext_vector_type(8)));
typedef float f32x4 __attribute__((ext_vector_type(4)));

__device__ inline unsigned short f2bf(float f) {
    union { float f; unsigned u; } v; v.f = f;
    unsigned r = v.u + 0x7fff + ((v.u >> 16) & 1);   // RNE
    return (unsigned short)(r >> 16);
}

// ---------------------------------------------------------------------------
// K0: weight transpose/cast + combined bias table
// wqkv_t[n][k] (576x192 bf16), wproj_t[n][k] (192x192 bf16),
// comb[w][h][r][c] = rpbt[relidx(r,c)][h] + mask[w][r][c]  (64*6*64*64 fp32)
// ---------------------------------------------------------------------------
__global__ __launch_bounds__(256) void prep_kernel(
    const float* __restrict__ w_qkv, const float* __restrict__ w_proj,
    const float* __restrict__ rpbt, const float* __restrict__ mask,
    unsigned short* __restrict__ wqkv_t, unsigned short* __restrict__ wproj_t,
    float* __restrict__ comb) {
    int idx = blockIdx.x * 256 + threadIdx.x;
    if (idx < 576 * 192) {
        int n = idx / 192, k = idx % 192;
        wqkv_t[idx] = f2bf(w_qkv[k * 576 + n]);
        return;
    }
    int i2 = idx - 576 * 192;
    if (i2 < 192 * 192) {
        int n = i2 / 192, k = i2 % 192;
        wproj_t[i2] = f2bf(w_proj[k * 192 + n]);
        return;
    }
    int i3 = i2 - 192 * 192;
    if (i3 < 64 * NH * NTOK * NTOK) {
        int c = i3 & 63, r = (i3 >> 6) & 63;
        int h = (i3 >> 12) % NH;
        int w = i3 / (NH * 4096);
        int rr = (r >> 3) - (c >> 3) + 7;     // row-coord delta (0..14)
        int cc = (r & 7) - (c & 7) + 7;       // col-coord delta (0..14)
        comb[i3] = rpbt[(rr * 15 + cc) * NH + h] + mask[w * 4096 + r * 64 + c];
    }
}

// ---------------------------------------------------------------------------
// K1: qkv projection. One block per window. X(64x192 fp32) -> LDS bf16 (pad 200).
// Loops over 3 column chunks (q,k,v), K-loop 6 steps of 32, staging
// wqkv_t slice (192 n x 32 k) into LDS (rows padded to 40).
// Wave w covers cols [48w,48w+48): 4 m-tiles x 3 n-tiles, 48 acc VGPRs.
// ---------------------------------------------------------------------------
__global__ __launch_bounds__(256) void qkv_kernel(
    const float* __restrict__ X, const unsigned short* __restrict__ Wt,
    const float* __restrict__ b_qkv,
    unsigned short* __restrict__ Qw, unsigned short* __restrict__ Kw,
    unsigned short* __restrict__ Vw) {
    __shared__ unsigned short lx[64 * 200];
    __shared__ unsigned short lw[192 * 40];
    const int tid = threadIdx.x;
    const int bwin = blockIdx.x;

    // stage X tile (64x192 fp32) as bf16
    const float4* xg = (const float4*)(X + (size_t)bwin * 64 * 192);
    for (int i = 0; i < 12; i++) {
        int e4 = tid + i * 256;            // 3072 float4
        int row = e4 / 48, c4 = e4 % 48;
        float4 v = xg[row * 48 + c4];
        union { unsigned short s[4]; uint2 u; } pk;
        pk.s[0] = f2bf(v.x); pk.s[1] = f2bf(v.y);
        pk.s[2] = f2bf(v.z); pk.s[3] = f2bf(v.w);
        *(uint2*)&lx[row * 200 + c4 * 4] = pk.u;
    }

    const int wave = tid >> 6, lane = tid & 63;
    const int l15 = lane & 15, quad = lane >> 4;

    for (int chunk = 0; chunk < 3; chunk++) {
        f32x4 acc[4][3];
        for (int mt = 0; mt < 4; mt++)
            for (int nt = 0; nt < 3; nt++)
                acc[mt][nt] = (f32x4){0.f, 0.f, 0.f, 0.f};

        for (int ks = 0; ks < 6; ks++) {
            __syncthreads();   // protects lw reuse (and lx on first pass)
            // stage W slice: n in [0,192) of this chunk, k in [32ks, 32ks+32)
            for (int i = 0; i < 3; i++) {
                int slot = tid + i * 256;          // 768 slots of 8 bf16
                int n = slot >> 2, koff = (slot & 3) * 8;
                *(uint4*)&lw[n * 40 + koff] =
                    *(const uint4*)&Wt[(chunk * 192 + n) * 192 + ks * 32 + koff];
            }
            __syncthreads();
            bf16x8 af[4], bfr[3];
            for (int mt = 0; mt < 4; mt++)
                af[mt] = *(const bf16x8*)&lx[(mt * 16 + l15) * 200 + ks * 32 + quad * 8];
            for (int nt = 0; nt < 3; nt++)
                bfr[nt] = *(const bf16x8*)&lw[(wave * 48 + nt * 16 + l15) * 40 + quad * 8];
            for (int mt = 0; mt < 4; mt++)
                for (int nt = 0; nt < 3; nt++)
                    acc[mt][nt] = __builtin_amdgcn_mfma_f32_16x16x32_bf16(
                        af[mt], bfr[nt], acc[mt][nt], 0, 0, 0);
        }

        // epilogue: C/D layout col=lane&15, row=(lane>>4)*4+reg
        unsigned short* dst = (chunk == 0) ? Qw : (chunk == 1) ? Kw : Vw;
        for (int nt = 0; nt < 3; nt++) {
            int cw = wave * 48 + nt * 16 + l15;        // 0..191 within chunk
            float bias = b_qkv[chunk * 192 + cw];
            int h = cw >> 5, d = cw & 31;
            size_t base = ((size_t)(bwin * NH + h)) * NTOK * HD + d;
            for (int mt = 0; mt < 4; mt++)
                for (int r = 0; r < 4; r++) {
                    int t = mt * 16 + quad * 4 + r;
                    dst[base + (size_t)t * HD] = f2bf(acc[mt][nt][r] + bias);
                }
        }
    }
}

// ---------------------------------------------------------------------------
// K2: attention. One block per (window, head). 4 waves; wave w owns query
// rows [16w,16w+16). S=QK^T (4 MFMA/wave), softmax in registers via 16-lane
// shfl_xor (row = quad*4+reg lives in a 16-consecutive-lane group), P->LDS
// bf16, PV (4 MFMA/wave), normalize by row-sum, write x_att bf16 (B,N,192).
// ---------------------------------------------------------------------------
__global__ __launch_bounds__(256) void attn_kernel(
    const unsigned short* __restrict__ Qw, const unsigned short* __restrict__ Kw,
    const unsigned short* __restrict__ Vw, const float* __restrict__ comb,
    unsigned short* __restrict__ xatt) {
    __shared__ unsigned short lq[64 * 40];
    __shared__ unsigned short lk[64 * 40];
    __shared__ unsigned short lvt[32 * 72];    // V transposed [d][token]
    __shared__ unsigned short lsp[64 * 72];    // P bf16 [row][key]
    __shared__ float lcomb[4096];

    const int tid = threadIdx.x;
    const int bwh = blockIdx.x;           // bwin*6 + h
    const int bwin = bwh / NH, h = bwh % NH;

    // stage Q, K, V(transposed)
    {
        int e = tid * 8;                   // 2048 bf16 each
        int t = e >> 5, d = e & 31;
        const unsigned short* qg = Qw + (size_t)bwh * 2048;
        const unsigned short* kg = Kw + (size_t)bwh * 2048;
        const unsigned short* vg = Vw + (size_t)bwh * 2048;
        *(uint4*)&lq[t * 40 + d] = *(const uint4*)&qg[e];
        *(uint4*)&lk[t * 40 + d] = *(const uint4*)&kg[e];
        union { uint4 u; unsigned short s[8]; } vv;
        vv.u = *(const uint4*)&vg[e];
        for (int j = 0; j < 8; j++) lvt[(d + j) * 72 + t] = vv.s[j];
    }
    // stage comb (bias+mask) slice: 4096 fp32
    {
        const float4* cg = (const float4*)(comb + ((size_t)(bwin & 63) * NH + h) * 4096);
        for (int i = 0; i < 4; i++)
            ((float4*)lcomb)[tid + i * 256] = cg[tid + i * 256];
    }
    __syncthreads();

    const int wave = tid >> 6, lane = tid & 63;
    const int l15 = lane & 15, quad = lane >> 4;
    const int mbase = wave * 16;

    // S = Q K^T  (K=32, one MFMA per n-tile)
    bf16x8 aq = *(const bf16x8*)&lq[(mbase + l15) * 40 + quad * 8];
    f32x4 sacc[4];
    for (int j = 0; j < 4; j++) {
        bf16x8 bk = *(const bf16x8*)&lk[(j * 16 + l15) * 40 + quad * 8];
        f32x4 z = (f32x4){0.f, 0.f, 0.f, 0.f};
        sacc[j] = __builtin_amdgcn_mfma_f32_16x16x32_bf16(aq, bk, z, 0, 0, 0);
    }

    // softmax (fp32, registers). s[j][r]: row = mbase+quad*4+r, col = j*16+l15
    float s[4][4];
    for (int j = 0; j < 4; j++)
        for (int r = 0; r < 4; r++)
            s[j][r] = sacc[j][r] * SCALE + lcomb[(mbase + quad * 4 + r) * 64 + j * 16 + l15];
    float p[4][4], rsum[4];
    for (int r = 0; r < 4; r++) {
        float m = fmaxf(fmaxf(s[0][r], s[1][r]), fmaxf(s[2][r], s[3][r]));
        for (int o = 1; o < 16; o <<= 1) m = fmaxf(m, __shfl_xor(m, o, 64));
        for (int j = 0; j < 4; j++) p[j][r] = __expf(s[j][r] - m);
        float su = p[0][r] + p[1][r] + p[2][r] + p[3][r];
        for (int o = 1; o < 16; o <<= 1) su += __shfl_xor(su, o, 64);
        rsum[r] = su;
    }
    // P (unnormalized) -> LDS bf16 in A-operand layout [row][key]
    for (int j = 0; j < 4; j++)
        for (int r = 0; r < 4; r++)
            lsp[(mbase + quad * 4 + r) * 72 + j * 16 + l15] = f2bf(p[j][r]);
    __syncthreads();

    // O = P V   (K=64 -> 2 k-steps, 2 n-tiles of d)
    f32x4 oacc[2];
    oacc[0] = (f32x4){0.f, 0.f, 0.f, 0.f};
    oacc[1] = (f32x4){0.f, 0.f, 0.f, 0.f};
    for (int kstep = 0; kstep < 2; kstep++) {
        bf16x8 ap = *(const bf16x8*)&lsp[(mbase + l15) * 72 + kstep * 32 + quad * 8];
        for (int n2 = 0; n2 < 2; n2++) {
            bf16x8 bv = *(const bf16x8*)&lvt[(n2 * 16 + l15) * 72 + kstep * 32 + quad * 8];
            oacc[n2] = __builtin_amdgcn_mfma_f32_16x16x32_bf16(ap, bv, oacc[n2], 0, 0, 0);
        }
    }
    // normalize + store: rsum[r] matches row = mbase+quad*4+r exactly
    unsigned short* og = xatt + (size_t)bwin * NTOK * WDIM + h * HD;
    for (int r = 0; r < 4; r++) {
        float inv = 1.0f / rsum[r];
        int t = mbase + quad * 4 + r;
        for (int n2 = 0; n2 < 2; n2++)
            og[(size_t)t * WDIM + n2 * 16 + l15] = f2bf(oacc[n2][r] * inv);
    }
}

// ---------------------------------------------------------------------------
// K3: output projection. One block per window. x_att tile (bf16) -> LDS,
// wproj_t staged per k-step. fp32 output + bias.
// ---------------------------------------------------------------------------
__global__ __launch_bounds__(256) void proj_kernel(
    const unsigned short* __restrict__ Xa, const unsigned short* __restrict__ Wt,
    const float* __restrict__ b_proj, float* __restrict__ out) {
    __shared__ unsigned short lx[64 * 200];
    __shared__ unsigned short lw[192 * 40];
    const int tid = threadIdx.x;
    const int bwin = blockIdx.x;

    const unsigned short* xg = Xa + (size_t)bwin * 64 * 192;
    for (int i = 0; i < 6; i++) {
        int e8 = tid + i * 256;            // 1536 chunks of 8 bf16
        int row = e8 / 24, c8 = e8 % 24;
        *(uint4*)&lx[row * 200 + c8 * 8] = *(const uint4*)&xg[row * 192 + c8 * 8];
    }

    const int wave = tid >> 6, lane = tid & 63;
    const int l15 = lane & 15, quad = lane >> 4;

    f32x4 acc[4][3];
    for (int mt = 0; mt < 4; mt++)
        for (int nt = 0; nt < 3; nt++)
            acc[mt][nt] = (f32x4){0.f, 0.f, 0.f, 0.f};

    for (int ks = 0; ks < 6; ks++) {
        __syncthreads();
        for (int i = 0; i < 3; i++) {
            int slot = tid + i * 256;
            int n = slot >> 2, koff = (slot & 3) * 8;
            *(uint4*)&lw[n * 40 + koff] = *(const uint4*)&Wt[n * 192 + ks * 32 + koff];
        }
        __syncthreads();
        bf16x8 af[4], bfr[3];
        for (int mt = 0; mt < 4; mt++)
            af[mt] = *(const bf16x8*)&lx[(mt * 16 + l15) * 200 + ks * 32 + quad * 8];
        for (int nt = 0; nt < 3; nt++)
            bfr[nt] = *(const bf16x8*)&lw[(wave * 48 + nt * 16 + l15) * 40 + quad * 8];
        for (int mt = 0; mt < 4; mt++)
            for (int nt = 0; nt < 3; nt++)
                acc[mt][nt] = __builtin_amdgcn_mfma_f32_16x16x32_bf16(
                    af[mt], bfr[nt], acc[mt][nt], 0, 0, 0);
    }

    for (int nt = 0; nt < 3; nt++) {
        int cw = wave * 48 + nt * 16 + l15;       // 0..191
        float bias = b_proj[cw];
        for (int mt = 0; mt < 4; mt++)
            for (int r = 0; r < 4; r++) {
                int t = mt * 16 + quad * 4 + r;
                out[((size_t)bwin * 64 + t) * 192 + cw] = acc[mt][nt][r] + bias;
            }
    }
}

// ---------------------------------------------------------------------------
extern "C" void kernel_launch(void* const* d_in, const int* in_sizes, int n_in,
                              void* d_out, int out_size, void* d_ws, size_t ws_size,
                              hipStream_t stream) {
    const float* x      = (const float*)d_in[0];
    const float* mask   = (const float*)d_in[1];
    const float* w_qkv  = (const float*)d_in[2];
    const float* b_qkv  = (const float*)d_in[3];
    const float* rpbt   = (const float*)d_in[4];
    const float* w_proj = (const float*)d_in[5];
    const float* b_proj = (const float*)d_in[6];
    float* out = (float*)d_out;

    const int B = in_sizes[0] / (NTOK * WDIM);   // 2048

    char* ws = (char*)d_ws;
    size_t o = 0;
    unsigned short* Qw = (unsigned short*)(ws + o); o += (size_t)B * NH * NTOK * HD * 2;
    unsigned short* Kw = (unsigned short*)(ws + o); o += (size_t)B * NH * NTOK * HD * 2;
    unsigned short* Vw = (unsigned short*)(ws + o); o += (size_t)B * NH * NTOK * HD * 2;
    unsigned short* Xa = (unsigned short*)(ws + o); o += (size_t)B * NTOK * WDIM * 2;
    unsigned short* Wq = (unsigned short*)(ws + o); o += 576 * 192 * 2;
    unsigned short* Wp = (unsigned short*)(ws + o); o += 192 * 192 * 2;
    float* comb        = (float*)(ws + o);         o += (size_t)64 * NH * NTOK * NTOK * 4;

    const int prep_elems = 576 * 192 + 192 * 192 + 64 * NH * NTOK * NTOK;
    prep_kernel<<<(prep_elems + 255) / 256, 256, 0, stream>>>(
        w_qkv, w_proj, rpbt, mask, Wq, Wp, comb);
    qkv_kernel<<<B, 256, 0, stream>>>(x, Wq, b_qkv, Qw, Kw, Vw);
    attn_kernel<<<B * NH, 256, 0, stream>>>(Qw, Kw, Vw, comb, Xa);
    proj_kernel<<<B, 256, 0, stream>>>(Xa, Wp, b_proj, out);
}